// Round 8
// baseline (60556.836 us; speedup 1.0000x reference)
//
#include <hip/hip_runtime.h>
#include <hip/hip_cooperative_groups.h>
#include <math.h>

namespace cg = cooperative_groups;

#define TSTEPS 1024
#define NITER  1027

typedef __attribute__((ext_vector_type(8))) short s8v;   // bf16x8 MFMA frag
typedef __attribute__((ext_vector_type(4))) float f4v;   // f32x4 acc

// ---- ws byte offsets ----
// W1F [16kt][64jt][2spl] 1KB frags ; W0F [9][64][2] ; FCF [8][16][2]
// H0F/H1F [2 par][8kt][16rt][2spl]  (h as bf16 hi/lo in A-frag layout)
// B0S/B1S [256 jh][4 gate] f32 summed biases ; PB [2][16][256] f32
#define OW1F 0u
#define OW0F 2097152u
#define OFCF 3276800u
#define OH0F 3538944u
#define OH1F 4063232u
#define OB0S 4587520u
#define OB1S 4591616u
#define OPB  4595712u
#define HPAR 262144u

#define MFMA(A,B,C) __builtin_amdgcn_mfma_f32_16x16x32_bf16(A, B, C, 0, 0, 0)

__device__ __forceinline__ short bf_hi(float v) {
    unsigned u = __builtin_bit_cast(unsigned, v);
    unsigned r = (u + 0x7FFFu + ((u >> 16) & 1u)) >> 16;
    return (short)r;
}
__device__ __forceinline__ float bf_f(short h) {
    unsigned u = ((unsigned)(unsigned short)h) << 16;
    return __builtin_bit_cast(float, u);
}
__device__ __forceinline__ float fast_sigmoid(float v) {
    return __builtin_amdgcn_rcpf(1.0f + __expf(-v));
}
__device__ __forceinline__ float fast_tanh(float v) {
    return 1.0f - 2.0f * __builtin_amdgcn_rcpf(1.0f + __expf(2.0f * v));
}

// ---- prep: pack weight B-frags (bf16 hi/lo), biases, zero h-frags ----
// consistency-only k-map within a 32-k tile: kw = 4g + (e&3) + 16*(e>>2)
#define NSH_W1 1048576u
#define NSH_W0 589824u
#define NSH_FC 131072u
#define NSH_TOT 1769472u
#define NFL_H 262144u
#define NFL_TOT 272384u

__global__ __launch_bounds__(256) void prep_kernel(
    const float* __restrict__ Wih0, const float* __restrict__ Whh0,
    const float* __restrict__ bih0, const float* __restrict__ bhh0,
    const float* __restrict__ Wih1, const float* __restrict__ Whh1,
    const float* __restrict__ bih1, const float* __restrict__ bhh1,
    const float* __restrict__ fc1w,
    char* __restrict__ ws)
{
    const unsigned NTOT = NSH_TOT + NFL_TOT;
    for (unsigned idx = blockIdx.x * blockDim.x + threadIdx.x; idx < NTOT;
         idx += gridDim.x * blockDim.x) {
        if (idx < NSH_TOT) {
            unsigned i2, mode, off;
            if (idx < NSH_W1)               { i2 = idx;                  mode = 0; off = OW1F; }
            else if (idx < NSH_W1 + NSH_W0) { i2 = idx - NSH_W1;         mode = 1; off = OW0F; }
            else                            { i2 = idx - NSH_W1 - NSH_W0; mode = 2; off = OFCF; }
            unsigned frag = i2 >> 9, el = i2 & 511u;
            unsigned lane = el >> 3, e = el & 7u;
            unsigned spl = frag & 1u, jtw = frag >> 1;
            unsigned n = lane & 15u, g = lane >> 4;
            unsigned kw = 4u*g + (e & 3u) + ((e >> 2) << 4);
            float w = 0.f;
            if (mode == 2) {
                unsigned jt = jtw & 15u, kt = frag >> 5;
                unsigned row = jt*16u + n;                        // fc1 output
                w = fc1w[row*256u + kt*32u + kw];
            } else {
                unsigned jt = jtw & 63u, kt = frag >> 7;
                unsigned row = (n & 3u)*256u + jt*4u + (n >> 2);  // gate-interleaved j'
                unsigned kg = kt*32u + kw;
                if (mode == 0) {
                    w = (kg < 256u) ? Wih1[row*256u + kg] : Whh1[row*256u + (kg - 256u)];
                } else {
                    if (kt == 0u) w = (kw < 16u) ? Wih0[row*16u + kw] : 0.f;
                    else          w = Whh0[row*256u + (kg - 32u)];
                }
            }
            short hv = bf_hi(w);
            short val = spl ? bf_hi(w - bf_f(hv)) : hv;
            *(short*)(ws + off + (size_t)frag*1024u + (size_t)el*2u) = val;
        } else {
            unsigned f = idx - NSH_TOT;
            if (f < NFL_H) {
                *(float*)(ws + OH0F + (size_t)f*4u) = 0.f;         // zero H0F+H1F (both parities)
            } else if (f < NFL_H + 1024u) {
                unsigned i3 = f - NFL_H, jh = i3 >> 2, gq = i3 & 3u;
                ((float*)(ws + OB0S))[i3] = bih0[gq*256u + jh] + bhh0[gq*256u + jh];
            } else if (f < NFL_H + 2048u) {
                unsigned i3 = f - NFL_H - 1024u, jh = i3 >> 2, gq = i3 & 3u;
                ((float*)(ws + OB1S))[i3] = bih1[gq*256u + jh] + bhh1[gq*256u + jh];
            } else {
                unsigned i3 = f - NFL_H - 2048u;
                ((float*)(ws + OPB))[i3] = 0.f;
            }
        }
    }
}

// ---- fused persistent roles, 256 blocks x 256 threads (coop-launch safe) ----
// blocks [0,128)   : L1 LSTM step i-1. block: 2 jt x 4 rt; wave: 1 jt x 2 rt.
// blocks [128,256) : L0 LSTM step i  + FC(fc1/relu/fc2 partials) step i-2.
//                    block 128 additionally writes out for step i-3.
template<bool ISL1>
__device__ __forceinline__ void lstm_role(
    const float* __restrict__ x,
    const float* __restrict__ fc1b, const float* __restrict__ fc2w,
    const float* __restrict__ fc2b,
    char* __restrict__ ws, float* __restrict__ out,
    cg::grid_group& grid, int blk, int wv, int lane, float* fcs)
{
    constexpr int NKT = ISL1 ? 16 : 9;
    const int b = blk & 127;
    const int jt = (b >> 2)*2 + (wv >> 1);
    const int rt0 = (b & 3)*4 + 2*(wv & 1);
    const int n15 = lane & 15, g4 = lane >> 4, q = lane & 3;
    const int jh = jt*4 + (n15 >> 2);

    s8v Bh[NKT], Bl[NKT];
    {
        const char* wb = ws + (ISL1 ? OW1F : OW0F);
        #pragma unroll
        for (int kt = 0; kt < NKT; ++kt) {
            const char* fb = wb + ((size_t)(kt*64 + jt)*2u)*1024u + (size_t)lane*16u;
            Bh[kt] = *(const s8v*)fb;
            Bl[kt] = *(const s8v*)(fb + 1024u);
        }
    }
    const float4 bsv = *(const float4*)(ws + (ISL1 ? OB1S : OB0S) + (size_t)jh*16u);
    float c0[4] = {0,0,0,0}, c1[4] = {0,0,0,0};

    // ---- FC setup (L0 blocks only) ----
    int fjt = 0, frt0 = 0;
    s8v Fh[2], Fl[2];
    float fb1 = 0.f, fw2 = 0.f, f2b0 = 0.f;
    if (!ISL1) {
        fjt = b >> 3; frt0 = (b & 7)*2;
        #pragma unroll
        for (int kl = 0; kl < 2; ++kl) {
            const int kt = 2*wv + kl;
            const char* fb = ws + OFCF + ((size_t)(kt*16 + fjt)*2u)*1024u + (size_t)lane*16u;
            Fh[kl] = *(const s8v*)fb;
            Fl[kl] = *(const s8v*)(fb + 1024u);
        }
        fb1  = fc1b[fjt*16 + n15];
        fw2  = fc2w[fjt*16 + n15];
        f2b0 = fc2b[0];
    }

    for (int i = 0; i < NITER; ++i) {
        const int s = ISL1 ? (i - 1) : i;
        if (s >= 0 && s < TSTEPS) {
            const char* h0r = ws + OH0F + (unsigned)((ISL1 ? s : (s + 1)) & 1) * HPAR;
            const char* h1r = ws + OH1F + (unsigned)((s + 1) & 1) * HPAR;
            f4v acc0 = {0,0,0,0}, acc1 = {0,0,0,0};

            if (!ISL1) {   // x-projection tile (kt 0): [x(16) | 16 zero-pad]
                #pragma unroll
                for (int d = 0; d < 2; ++d) {
                    const int rt = rt0 + d;
                    const int r = rt*16 + n15;
                    const float4 xv = *(const float4*)(x + ((size_t)r*TSTEPS + s)*16u + 4u*(unsigned)g4);
                    float xs[4] = {xv.x, xv.y, xv.z, xv.w};
                    s8v ah, al;
                    #pragma unroll
                    for (int e2 = 0; e2 < 4; ++e2) {
                        short hv = bf_hi(xs[e2]);
                        ah[e2] = hv; al[e2] = bf_hi(xs[e2] - bf_f(hv));
                        ah[e2 + 4] = 0; al[e2 + 4] = 0;
                    }
                    if (d == 0) {
                        acc0 = MFMA(ah, Bh[0], acc0); acc0 = MFMA(al, Bh[0], acc0);
                        acc0 = MFMA(ah, Bl[0], acc0); acc0 = MFMA(al, Bl[0], acc0);
                    } else {
                        acc1 = MFMA(ah, Bh[0], acc1); acc1 = MFMA(al, Bh[0], acc1);
                        acc1 = MFMA(ah, Bl[0], acc1); acc1 = MFMA(al, Bl[0], acc1);
                    }
                }
            }

            constexpr int KT0 = ISL1 ? 0 : 1;
            auto lda = [&](int kt, int rt, int spl) -> s8v {
                const char* hb; int ktl;
                if (ISL1) { if (kt < 8) { hb = h0r; ktl = kt; } else { hb = h1r; ktl = kt - 8; } }
                else      { hb = h0r; ktl = kt - 1; }
                return *(const s8v*)(hb + ((size_t)(ktl*16 + rt)*2u + (unsigned)spl)*1024u
                                        + (size_t)lane*16u);
            };
            s8v a0h = lda(KT0, rt0, 0),     a0l = lda(KT0, rt0, 1);
            s8v a1h = lda(KT0, rt0 + 1, 0), a1l = lda(KT0, rt0 + 1, 1);
            #pragma unroll
            for (int kt = KT0; kt < NKT; ++kt) {
                s8v p0h, p0l, p1h, p1l;
                if (kt + 1 < NKT) {
                    p0h = lda(kt + 1, rt0, 0);     p0l = lda(kt + 1, rt0, 1);
                    p1h = lda(kt + 1, rt0 + 1, 0); p1l = lda(kt + 1, rt0 + 1, 1);
                }
                acc0 = MFMA(a0h, Bh[kt], acc0); acc0 = MFMA(a0l, Bh[kt], acc0);
                acc0 = MFMA(a0h, Bl[kt], acc0); acc0 = MFMA(a0l, Bl[kt], acc0);
                acc1 = MFMA(a1h, Bh[kt], acc1); acc1 = MFMA(a1l, Bh[kt], acc1);
                acc1 = MFMA(a1h, Bl[kt], acc1); acc1 = MFMA(a1l, Bl[kt], acc1);
                a0h = p0h; a0l = p0l; a1h = p1h; a1l = p1l;
            }

            // cell update: D lane holds col j'=n15, rows m=4*g4+e. Quad shuffles gather gates.
            char* hwb = ws + (ISL1 ? OH1F : OH0F) + (unsigned)(s & 1) * HPAR;
            const int ktt = jh >> 5, kwt = jh & 31;
            const int gp = (kwt & 15) >> 2;
            const int ep = (kwt & 3) + ((kwt >> 4) << 2);
            #pragma unroll
            for (int d = 0; d < 2; ++d) {
                const int rt = rt0 + d;
                f4v av = d ? acc1 : acc0;
                float* cc = d ? c1 : c0;
                char* fb = hwb + ((size_t)(ktt*16 + rt)*2u)*1024u;
                #pragma unroll
                for (int e = 0; e < 4; ++e) {
                    float v0 = av[e];
                    float v1 = __shfl_xor(v0, 1);
                    float v2 = __shfl_xor(v0, 2);
                    float v3 = __shfl_xor(v1, 2);
                    float gi = (q==0)? v0 : (q==1)? v1 : (q==2)? v2 : v3;
                    float gf = (q==0)? v1 : (q==1)? v0 : (q==2)? v3 : v2;
                    float gg = (q==0)? v2 : (q==1)? v3 : (q==2)? v0 : v1;
                    float go = (q==0)? v3 : (q==1)? v2 : (q==2)? v1 : v0;
                    float ig = fast_sigmoid(gi + bsv.x);
                    float fg = fast_sigmoid(gf + bsv.y);
                    float gt = fast_tanh   (gg + bsv.z);
                    float og = fast_sigmoid(go + bsv.w);
                    float cn = fg * cc[e] + ig * gt;
                    cc[e] = cn;
                    float h = og * fast_tanh(cn);
                    if (q == 0) {
                        const int m = 4*g4 + e;
                        short hv = bf_hi(h);
                        short lv = bf_hi(h - bf_f(hv));
                        *(short*)(fb + (size_t)(m + 16*gp)*16u + (size_t)ep*2u) = hv;
                        *(short*)(fb + 1024u + (size_t)(m + 16*gp)*16u + (size_t)ep*2u) = lv;
                    }
                }
            }
        }

        if (!ISL1) {
            // ---- FC: fc1+relu+fc2 partials for step i-2 ----
            const int sf = i - 2;
            const bool fact = (sf >= 0) && (sf < TSTEPS);
            f4v fa0 = {0,0,0,0}, fa1 = {0,0,0,0};
            if (fact) {
                const char* h1r = ws + OH1F + (unsigned)(sf & 1) * HPAR;
                #pragma unroll
                for (int kl = 0; kl < 2; ++kl) {
                    const int kt = 2*wv + kl;
                    const char* base = h1r + ((size_t)(kt*16 + frt0)*2u)*1024u + (size_t)lane*16u;
                    s8v a0h = *(const s8v*)base;
                    s8v a0l = *(const s8v*)(base + 1024u);
                    s8v a1h = *(const s8v*)(base + 2048u);
                    s8v a1l = *(const s8v*)(base + 3072u);
                    fa0 = MFMA(a0h, Fh[kl], fa0); fa0 = MFMA(a0l, Fh[kl], fa0);
                    fa0 = MFMA(a0h, Fl[kl], fa0); fa0 = MFMA(a0l, Fl[kl], fa0);
                    fa1 = MFMA(a1h, Fh[kl], fa1); fa1 = MFMA(a1l, Fh[kl], fa1);
                    fa1 = MFMA(a1h, Fl[kl], fa1); fa1 = MFMA(a1l, Fl[kl], fa1);
                }
            }
            *(f4v*)&fcs[((wv*2 + 0)*64 + lane)*4] = fa0;
            *(f4v*)&fcs[((wv*2 + 1)*64 + lane)*4] = fa1;
            __syncthreads();
            if (fact && wv == 0) {
                #pragma unroll
                for (int d = 0; d < 2; ++d) {
                    f4v av = *(const f4v*)&fcs[((0*2 + d)*64 + lane)*4];
                    av = av + *(const f4v*)&fcs[((1*2 + d)*64 + lane)*4];
                    av = av + *(const f4v*)&fcs[((2*2 + d)*64 + lane)*4];
                    av = av + *(const f4v*)&fcs[((3*2 + d)*64 + lane)*4];
                    const int rt = frt0 + d;
                    float* pb = (float*)(ws + OPB) + (unsigned)(i & 1)*4096u + fjt*256 + rt*16;
                    #pragma unroll
                    for (int e = 0; e < 4; ++e) {
                        float v = av[e] + fb1;
                        v = v > 0.f ? v : 0.f;
                        float p = v * fw2;
                        p += __shfl_xor(p, 1);
                        p += __shfl_xor(p, 2);
                        p += __shfl_xor(p, 4);
                        p += __shfl_xor(p, 8);
                        if (n15 == 0) pb[4*g4 + e] = p;
                    }
                }
            }
            // ---- out: final fc2 reduce for step i-3 (block 128 only) ----
            if (b == 0 && i >= 3) {
                const int tt = i - 3;
                const float* pb = (float*)(ws + OPB) + (unsigned)((i - 1) & 1)*4096u;
                const int tid = wv*64 + lane;
                float ssum = f2b0;
                #pragma unroll
                for (int jx = 0; jx < 16; ++jx) ssum += pb[jx*256 + tid];
                out[(size_t)tid*TSTEPS + tt] = ssum;
            }
        }
        __threadfence();
        grid.sync();
    }
}

__global__ __launch_bounds__(256, 1) void lstm_mfma(
    const float* __restrict__ x, const float* __restrict__ fc1b,
    const float* __restrict__ fc2w, const float* __restrict__ fc2b,
    char* __restrict__ ws, float* __restrict__ out)
{
    cg::grid_group grid = cg::this_grid();
    __shared__ __align__(16) float fcs[2048];
    const int tid = threadIdx.x;
    const int lane = tid & 63;
    const int wv = __builtin_amdgcn_readfirstlane(tid >> 6);
    const int blk = blockIdx.x;
    if (blk < 128) lstm_role<true >(x, fc1b, fc2w, fc2b, ws, out, grid, blk, wv, lane, fcs);
    else           lstm_role<false>(x, fc1b, fc2w, fc2b, ws, out, grid, blk, wv, lane, fcs);
}

extern "C" void kernel_launch(void* const* d_in, const int* in_sizes, int n_in,
                              void* d_out, int out_size, void* d_ws, size_t ws_size,
                              hipStream_t stream)
{
    const float* x    = (const float*)d_in[0];
    const float* Wih0 = (const float*)d_in[1];
    const float* Whh0 = (const float*)d_in[2];
    const float* bih0 = (const float*)d_in[3];
    const float* bhh0 = (const float*)d_in[4];
    const float* Wih1 = (const float*)d_in[5];
    const float* Whh1 = (const float*)d_in[6];
    const float* bih1 = (const float*)d_in[7];
    const float* bhh1 = (const float*)d_in[8];
    const float* fc1w = (const float*)d_in[9];
    const float* fc1b = (const float*)d_in[10];
    const float* fc2w = (const float*)d_in[11];
    const float* fc2b = (const float*)d_in[12];
    char*  ws  = (char*)d_ws;
    float* out = (float*)d_out;

    prep_kernel<<<1024, 256, 0, stream>>>(Wih0, Whh0, bih0, bhh0,
                                          Wih1, Whh1, bih1, bhh1, fc1w, ws);

    void* args[] = {(void*)&x, (void*)&fc1b, (void*)&fc2w, (void*)&fc2b,
                    (void*)&ws, (void*)&out};
    hipLaunchCooperativeKernel((const void*)lstm_mfma, dim3(256), dim3(256),
                               args, 0, stream);
}

// Round 9
// 18570.247 us; speedup vs baseline: 3.2610x; 3.2610x over previous
//
#include <hip/hip_runtime.h>
#include <math.h>

#define TSTEPS 1024
#define NITER  1027

typedef __attribute__((ext_vector_type(8))) short s8v;   // bf16x8 MFMA frag
typedef __attribute__((ext_vector_type(4))) float f4v;   // f32x4 acc

// ---- ws byte offsets ----
// W1F [16kt][64jt][2spl] 1KB frags ; W0F [9][64][2] ; FCF [8][16][2]
// H0P/H1P [2 parity][256 j][256 r] u32 = (bf16hi<<16)|bf16lo
// B0S/B1S [256 jh][4 gate] f32 ; PB [2][16][256] f32 ; CNT barrier counter
#define OW1F 0u
#define OW0F 2097152u
#define OFCF 3276800u
#define OH0P 3538944u
#define OH1P 4063232u
#define OB0S 4587520u
#define OB1S 4591616u
#define OPB  4595712u
#define OCNT 4628480u

#define MFMA(A,B,C) __builtin_amdgcn_mfma_f32_16x16x32_bf16(A, B, C, 0, 0, 0)

__device__ __forceinline__ short bf_hi(float v) {
    unsigned u = __builtin_bit_cast(unsigned, v);
    unsigned r = (u + 0x7FFFu + ((u >> 16) & 1u)) >> 16;
    return (short)r;
}
__device__ __forceinline__ float bf_f(short h) {
    unsigned u = ((unsigned)(unsigned short)h) << 16;
    return __builtin_bit_cast(float, u);
}
__device__ __forceinline__ float fast_sigmoid(float v) {
    return __builtin_amdgcn_rcpf(1.0f + __expf(-v));
}
__device__ __forceinline__ float fast_tanh(float v) {
    return 1.0f - 2.0f * __builtin_amdgcn_rcpf(1.0f + __expf(2.0f * v));
}

// ---- prep: pack weight B-frags (bf16 hi/lo), biases, zero h planes ----
// consistency-only k-map within a 32-k tile: kw = 4g + (e&3) + 16*(e>>2)
#define NSH_W1 1048576u
#define NSH_W0 589824u
#define NSH_TOT 1769472u
#define NTAIL 273408u

__global__ __launch_bounds__(256) void prep_kernel(
    const float* __restrict__ Wih0, const float* __restrict__ Whh0,
    const float* __restrict__ bih0, const float* __restrict__ bhh0,
    const float* __restrict__ Wih1, const float* __restrict__ Whh1,
    const float* __restrict__ bih1, const float* __restrict__ bhh1,
    const float* __restrict__ fc1w,
    char* __restrict__ ws)
{
    const unsigned NTOT = NSH_TOT + NTAIL;
    for (unsigned idx = blockIdx.x * blockDim.x + threadIdx.x; idx < NTOT;
         idx += gridDim.x * blockDim.x) {
        if (idx < NSH_TOT) {
            unsigned i2, mode, off;
            if (idx < NSH_W1)               { i2 = idx;                  mode = 0; off = OW1F; }
            else if (idx < NSH_W1 + NSH_W0) { i2 = idx - NSH_W1;         mode = 1; off = OW0F; }
            else                            { i2 = idx - NSH_W1 - NSH_W0; mode = 2; off = OFCF; }
            unsigned frag = i2 >> 9, el = i2 & 511u;
            unsigned lane = el >> 3, e = el & 7u;
            unsigned spl = frag & 1u, jtw = frag >> 1;
            unsigned n = lane & 15u, g = lane >> 4;
            unsigned kw = 4u*g + (e & 3u) + ((e >> 2) << 4);
            float w = 0.f;
            if (mode == 2) {
                unsigned jt = jtw & 15u, kt = frag >> 5;
                unsigned row = jt*16u + n;                        // fc1 output
                w = fc1w[row*256u + kt*32u + kw];
            } else {
                unsigned jt = jtw & 63u, kt = frag >> 7;
                unsigned row = (n & 3u)*256u + jt*4u + (n >> 2);  // gate-interleaved j'
                unsigned kg = kt*32u + kw;
                if (mode == 0) {
                    w = (kg < 256u) ? Wih1[row*256u + kg] : Whh1[row*256u + (kg - 256u)];
                } else {
                    if (kt == 0u) w = (kw < 16u) ? Wih0[row*16u + kw] : 0.f;
                    else          w = Whh0[row*256u + (kg - 32u)];
                }
            }
            short hv = bf_hi(w);
            short val = spl ? bf_hi(w - bf_f(hv)) : hv;
            *(short*)(ws + off + (size_t)frag*1024u + (size_t)el*2u) = val;
        } else {
            unsigned f = idx - NSH_TOT;
            if (f < 262144u) {
                ((unsigned*)(ws + OH0P))[f] = 0u;     // h0+h1 planes, both parities
            } else if (f < 263168u) {
                unsigned i3 = f - 262144u, jh = i3 >> 2, gq = i3 & 3u;
                ((float*)(ws + OB0S))[i3] = bih0[gq*256u + jh] + bhh0[gq*256u + jh];
            } else if (f < 264192u) {
                unsigned i3 = f - 263168u, jh = i3 >> 2, gq = i3 & 3u;
                ((float*)(ws + OB1S))[i3] = bih1[gq*256u + jh] + bhh1[gq*256u + jh];
            } else if (f < 272384u) {
                ((float*)(ws + OPB))[f - 264192u] = 0.f;
            } else {
                ((unsigned*)(ws + OCNT))[f - 272384u] = 0u;
            }
        }
    }
}

// gather 8 packed u32 for one A-frag pair: lanes (n15 -> r, g4 -> j group)
#define LDW(DST, KTL_, PLANE, RT) do { \
    const unsigned* bp_ = (PLANE) + (unsigned)(((KTL_)*32 + 4*g4)*256 + (RT)*16 + n15); \
    DST[0] = bp_[0];    DST[1] = bp_[256];  DST[2] = bp_[512];  DST[3] = bp_[768]; \
    DST[4] = bp_[4096]; DST[5] = bp_[4352]; DST[6] = bp_[4608]; DST[7] = bp_[4864]; \
  } while (0)

#define UNPK(AH, AL, W) do { \
    _Pragma("unroll") \
    for (int e_ = 0; e_ < 8; ++e_) { \
        AH[e_] = (short)(W[e_] >> 16); \
        AL[e_] = (short)(W[e_] & 0xffffu); \
    } \
  } while (0)

// ---- fused persistent roles, 256 blocks x 256 threads ----
// blocks [0,128)   : L1 LSTM step i-1. block: 2 jt x 4 rt; wave: 1 jt x 2 rt.
// blocks [128,256) : L0 LSTM step i + FC(fc1/relu/fc2) step i-2;
//                    block 128 also writes out for step i-3.
template<bool ISL1>
__device__ __forceinline__ void lstm_role(
    const float* __restrict__ x,
    const float* __restrict__ fc1b, const float* __restrict__ fc2w,
    const float* __restrict__ fc2b,
    char* __restrict__ ws, float* __restrict__ out,
    int blk, int wv, int lane, float* fcs)
{
    constexpr int NKT = ISL1 ? 16 : 9;
    const int tid = wv*64 + lane;
    const int b   = blk & 127;
    const int jt  = (b >> 2)*2 + (wv >> 1);
    const int rt0 = (b & 3)*4 + 2*(wv & 1);
    const int n15 = lane & 15, g4 = lane >> 4, q = lane & 3;
    const int jh  = jt*4 + (n15 >> 2);

    unsigned* const h0p = (unsigned*)(ws + OH0P);
    unsigned* const h1p = (unsigned*)(ws + OH1P);
    unsigned* const cnt = (unsigned*)(ws + OCNT);

    // stationary B-frags (stay in VGPRs: no calls inside the loop)
    s8v Bh[NKT], Bl[NKT];
    {
        const char* wb = ws + (ISL1 ? OW1F : OW0F);
        #pragma unroll
        for (int kt = 0; kt < NKT; ++kt) {
            const char* fb = wb + ((size_t)(kt*64 + jt)*2u)*1024u + (size_t)lane*16u;
            Bh[kt] = *(const s8v*)fb;
            Bl[kt] = *(const s8v*)(fb + 1024u);
        }
    }
    const float4 bsv = *(const float4*)(ws + (ISL1 ? OB1S : OB0S) + (size_t)jh*16u);
    float c0[4] = {0,0,0,0}, c1[4] = {0,0,0,0};

    // FC setup (L0 blocks only)
    int fjt = 0, frt0 = 0;
    s8v Fh[2], Fl[2];
    float fb1 = 0.f, fw2 = 0.f, f2b0 = 0.f;
    if (!ISL1) {
        fjt = b >> 3; frt0 = (b & 7)*2;
        #pragma unroll
        for (int kl = 0; kl < 2; ++kl) {
            const int kt = 2*wv + kl;
            const char* fb = ws + OFCF + ((size_t)(kt*16 + fjt)*2u)*1024u + (size_t)lane*16u;
            Fh[kl] = *(const s8v*)fb;
            Fl[kl] = *(const s8v*)(fb + 1024u);
        }
        fb1  = fc1b[fjt*16 + n15];
        fw2  = fc2w[fjt*16 + n15];
        f2b0 = fc2b[0];
    }

    #pragma unroll 1
    for (int i = 0; i < NITER; ++i) {
        const int s = ISL1 ? (i - 1) : i;
        if (s >= 0 && s < TSTEPS) {
            const unsigned* p0 = h0p + (unsigned)((ISL1 ? s : (s + 1)) & 1) * 65536u;
            const unsigned* p1 = h1p + (unsigned)((s + 1) & 1) * 65536u;
            f4v acc0 = {0,0,0,0}, acc1 = {0,0,0,0};

            if (!ISL1) {   // x-projection tile (kt 0): [x(16) | 16 zero-pad]
                #pragma unroll
                for (int d = 0; d < 2; ++d) {
                    const int rt = rt0 + d;
                    const int r = rt*16 + n15;
                    const float4 xv = *(const float4*)(x + ((size_t)r*TSTEPS + s)*16u + 4u*(unsigned)g4);
                    float xs[4] = {xv.x, xv.y, xv.z, xv.w};
                    s8v ah, al;
                    #pragma unroll
                    for (int e2 = 0; e2 < 4; ++e2) {
                        short hv = bf_hi(xs[e2]);
                        ah[e2] = hv; al[e2] = bf_hi(xs[e2] - bf_f(hv));
                        ah[e2 + 4] = 0; al[e2 + 4] = 0;
                    }
                    if (d == 0) {
                        acc0 = MFMA(ah, Bh[0], acc0); acc0 = MFMA(al, Bh[0], acc0);
                        acc0 = MFMA(ah, Bl[0], acc0); acc0 = MFMA(al, Bl[0], acc0);
                    } else {
                        acc1 = MFMA(ah, Bh[0], acc1); acc1 = MFMA(al, Bh[0], acc1);
                        acc1 = MFMA(ah, Bl[0], acc1); acc1 = MFMA(al, Bl[0], acc1);
                    }
                }
            }

            constexpr int KT0 = ISL1 ? 0 : 1;
            unsigned w0c[8] = {0,0,0,0,0,0,0,0}, w1c[8] = {0,0,0,0,0,0,0,0};
            unsigned w0n[8] = {0,0,0,0,0,0,0,0}, w1n[8] = {0,0,0,0,0,0,0,0};
            if (ISL1) { LDW(w0c, KT0, p0, rt0); LDW(w1c, KT0, p0, rt0 + 1); }
            else      { LDW(w0c, 0,   p0, rt0); LDW(w1c, 0,   p0, rt0 + 1); }
            #pragma unroll
            for (int kt = KT0; kt < NKT; ++kt) {
                if (kt + 1 < NKT) {
                    const int kn = kt + 1;
                    if (ISL1) {
                        if (kn < 8) { LDW(w0n, kn,     p0, rt0); LDW(w1n, kn,     p0, rt0 + 1); }
                        else        { LDW(w0n, kn - 8, p1, rt0); LDW(w1n, kn - 8, p1, rt0 + 1); }
                    } else        { LDW(w0n, kn - 1, p0, rt0); LDW(w1n, kn - 1, p0, rt0 + 1); }
                }
                s8v a0h, a0l, a1h, a1l;
                UNPK(a0h, a0l, w0c); UNPK(a1h, a1l, w1c);
                acc0 = MFMA(a0h, Bh[kt], acc0); acc0 = MFMA(a0l, Bh[kt], acc0);
                acc0 = MFMA(a0h, Bl[kt], acc0); acc0 = MFMA(a0l, Bl[kt], acc0);
                acc1 = MFMA(a1h, Bh[kt], acc1); acc1 = MFMA(a1l, Bh[kt], acc1);
                acc1 = MFMA(a1h, Bl[kt], acc1); acc1 = MFMA(a1l, Bl[kt], acc1);
                #pragma unroll
                for (int z = 0; z < 8; ++z) { w0c[z] = w0n[z]; w1c[z] = w1n[z]; }
            }

            // cell update: D lane holds col j'=n15, rows m=4*g4+e. Quad shuffles gather gates.
            unsigned* hwp = (ISL1 ? h1p : h0p) + (unsigned)(s & 1) * 65536u;
            #pragma unroll
            for (int d = 0; d < 2; ++d) {
                const int rt = rt0 + d;
                f4v av = d ? acc1 : acc0;
                float* cc = d ? c1 : c0;
                unsigned pk[4];
                #pragma unroll
                for (int e = 0; e < 4; ++e) {
                    float v0 = av[e];
                    float v1 = __shfl_xor(v0, 1);
                    float v2 = __shfl_xor(v0, 2);
                    float v3 = __shfl_xor(v1, 2);
                    float gi = (q==0)? v0 : (q==1)? v1 : (q==2)? v2 : v3;
                    float gf = (q==0)? v1 : (q==1)? v0 : (q==2)? v3 : v2;
                    float gg = (q==0)? v2 : (q==1)? v3 : (q==2)? v0 : v1;
                    float go = (q==0)? v3 : (q==1)? v2 : (q==2)? v1 : v0;
                    float ig = fast_sigmoid(gi + bsv.x);
                    float fg = fast_sigmoid(gf + bsv.y);
                    float gt = fast_tanh   (gg + bsv.z);
                    float og = fast_sigmoid(go + bsv.w);
                    float cn = fg * cc[e] + ig * gt;
                    cc[e] = cn;
                    float h = og * fast_tanh(cn);
                    short hv = bf_hi(h);
                    short lv = bf_hi(h - bf_f(hv));
                    pk[e] = ((unsigned)(unsigned short)hv << 16) | (unsigned)(unsigned short)lv;
                }
                if (q == 0) {
                    unsigned* dst = hwp + (unsigned)jh*256u + (unsigned)(rt*16 + 4*g4);
                    unsigned long long lo = ((unsigned long long)pk[1] << 32) | pk[0];
                    unsigned long long hi = ((unsigned long long)pk[3] << 32) | pk[2];
                    __hip_atomic_store((unsigned long long*)dst,       lo, __ATOMIC_RELAXED, __HIP_MEMORY_SCOPE_AGENT);
                    __hip_atomic_store((unsigned long long*)(dst + 2), hi, __ATOMIC_RELAXED, __HIP_MEMORY_SCOPE_AGENT);
                }
            }
        }

        if (!ISL1) {
            // ---- FC: fc1+relu+fc2 partials for step i-2 ----
            const int sf = i - 2;
            const bool fact = (sf >= 0) && (sf < TSTEPS);
            f4v fa0 = {0,0,0,0}, fa1 = {0,0,0,0};
            if (fact) {
                const unsigned* pf = h1p + (unsigned)(sf & 1) * 65536u;
                #pragma unroll
                for (int kl = 0; kl < 2; ++kl) {
                    const int kt = 2*wv + kl;
                    unsigned wa[8], wb2[8];
                    LDW(wa,  kt, pf, frt0);
                    LDW(wb2, kt, pf, frt0 + 1);
                    s8v a0h, a0l, a1h, a1l;
                    UNPK(a0h, a0l, wa); UNPK(a1h, a1l, wb2);
                    fa0 = MFMA(a0h, Fh[kl], fa0); fa0 = MFMA(a0l, Fh[kl], fa0);
                    fa0 = MFMA(a0h, Fl[kl], fa0); fa0 = MFMA(a0l, Fl[kl], fa0);
                    fa1 = MFMA(a1h, Fh[kl], fa1); fa1 = MFMA(a1l, Fh[kl], fa1);
                    fa1 = MFMA(a1h, Fl[kl], fa1); fa1 = MFMA(a1l, Fl[kl], fa1);
                }
            }
            *(f4v*)&fcs[((wv*2 + 0)*64 + lane)*4] = fa0;
            *(f4v*)&fcs[((wv*2 + 1)*64 + lane)*4] = fa1;
            __syncthreads();
            if (fact && wv == 0) {
                #pragma unroll
                for (int d = 0; d < 2; ++d) {
                    f4v av = *(const f4v*)&fcs[((0*2 + d)*64 + lane)*4];
                    av = av + *(const f4v*)&fcs[((1*2 + d)*64 + lane)*4];
                    av = av + *(const f4v*)&fcs[((2*2 + d)*64 + lane)*4];
                    av = av + *(const f4v*)&fcs[((3*2 + d)*64 + lane)*4];
                    float pe[4];
                    #pragma unroll
                    for (int e = 0; e < 4; ++e) {
                        float v = av[e] + fb1;
                        v = v > 0.f ? v : 0.f;
                        float p = v * fw2;
                        p += __shfl_xor(p, 1);
                        p += __shfl_xor(p, 2);
                        p += __shfl_xor(p, 4);
                        p += __shfl_xor(p, 8);
                        pe[e] = p;
                    }
                    if (n15 == 0) {
                        unsigned* pb = (unsigned*)(ws + OPB) + (unsigned)(i & 1)*4096u
                                       + (unsigned)(fjt*256 + (frt0 + d)*16 + 4*g4);
                        unsigned long long lo =
                            ((unsigned long long)__builtin_bit_cast(unsigned, pe[1]) << 32)
                            | __builtin_bit_cast(unsigned, pe[0]);
                        unsigned long long hi =
                            ((unsigned long long)__builtin_bit_cast(unsigned, pe[3]) << 32)
                            | __builtin_bit_cast(unsigned, pe[2]);
                        __hip_atomic_store((unsigned long long*)pb,       lo, __ATOMIC_RELAXED, __HIP_MEMORY_SCOPE_AGENT);
                        __hip_atomic_store((unsigned long long*)(pb + 2), hi, __ATOMIC_RELAXED, __HIP_MEMORY_SCOPE_AGENT);
                    }
                }
            }
            // ---- out: final fc2 reduce for step i-3 (block 128 only) ----
            if (b == 0 && i >= 3) {
                const int tt = i - 3;
                const float* pb = (const float*)(ws + OPB) + (unsigned)((i - 1) & 1)*4096u;
                float ssum = f2b0;
                #pragma unroll
                for (int jx = 0; jx < 16; ++jx) ssum += pb[jx*256 + tid];
                __hip_atomic_store((unsigned*)&out[(size_t)tid*TSTEPS + tt],
                                   __builtin_bit_cast(unsigned, ssum),
                                   __ATOMIC_RELAXED, __HIP_MEMORY_SCOPE_AGENT);
            }
        }

        // ---- lightweight grid barrier (no L2 flush, no calls) ----
        __syncthreads();   // drains vmcnt -> all sc1 stores ACKed at coherence point
        if (tid == 0) {
            __hip_atomic_fetch_add(cnt, 1u, __ATOMIC_RELAXED, __HIP_MEMORY_SCOPE_AGENT);
            const unsigned tgt = 256u * (unsigned)(i + 1);
            while (__hip_atomic_load(cnt, __ATOMIC_RELAXED, __HIP_MEMORY_SCOPE_AGENT) < tgt)
                __builtin_amdgcn_s_sleep(2);
        }
        __syncthreads();
        __builtin_amdgcn_fence(__ATOMIC_ACQUIRE, "agent");   // invalidate L1/L2 (no writeback)
    }
}

__global__ __launch_bounds__(256, 1) void lstm_mfma(
    const float* __restrict__ x, const float* __restrict__ fc1b,
    const float* __restrict__ fc2w, const float* __restrict__ fc2b,
    char* __restrict__ ws, float* __restrict__ out)
{
    __shared__ __align__(16) float fcs[2048];
    const int tid = threadIdx.x;
    const int lane = tid & 63;
    const int wv = __builtin_amdgcn_readfirstlane(tid >> 6);
    const int blk = blockIdx.x;
    if (blk < 128) lstm_role<true >(x, fc1b, fc2w, fc2b, ws, out, blk, wv, lane, fcs);
    else           lstm_role<false>(x, fc1b, fc2w, fc2b, ws, out, blk, wv, lane, fcs);
}

extern "C" void kernel_launch(void* const* d_in, const int* in_sizes, int n_in,
                              void* d_out, int out_size, void* d_ws, size_t ws_size,
                              hipStream_t stream)
{
    const float* x    = (const float*)d_in[0];
    const float* Wih0 = (const float*)d_in[1];
    const float* Whh0 = (const float*)d_in[2];
    const float* bih0 = (const float*)d_in[3];
    const float* bhh0 = (const float*)d_in[4];
    const float* Wih1 = (const float*)d_in[5];
    const float* Whh1 = (const float*)d_in[6];
    const float* bih1 = (const float*)d_in[7];
    const float* bhh1 = (const float*)d_in[8];
    const float* fc1w = (const float*)d_in[9];
    const float* fc1b = (const float*)d_in[10];
    const float* fc2w = (const float*)d_in[11];
    const float* fc2b = (const float*)d_in[12];
    char*  ws  = (char*)d_ws;
    float* out = (float*)d_out;

    prep_kernel<<<1024, 256, 0, stream>>>(Wih0, Whh0, bih0, bhh0,
                                          Wih1, Whh1, bih1, bhh1, fc1w, ws);

    void* args[] = {(void*)&x, (void*)&fc1b, (void*)&fc2w, (void*)&fc2b,
                    (void*)&ws, (void*)&out};
    hipLaunchCooperativeKernel((const void*)lstm_mfma, dim3(256), dim3(256),
                               args, 0, stream);
}